// Round 8
// baseline (341.015 us; speedup 1.0000x reference)
//
#include <hip/hip_runtime.h>
#include <hip/hip_bf16.h>

#define NN 4096
#define CC 128

typedef __bf16 bf16x8_t __attribute__((ext_vector_type(8)));
typedef __bf16 bf16x4_t __attribute__((ext_vector_type(4)));
typedef float f32x4 __attribute__((ext_vector_type(4)));

static constexpr float SCALE = 0.17677669529663687f;  // 32^-0.5
static constexpr float BN_EPS = 1e-3f;

// ---------------- precompute: fold BN into pointwise weights ----------------
struct PrecompArgs {
    const float *g[3], *b[3], *mu[3], *var[3], *dwb[3], *pwk[3], *pwb[3];
    float *Wp[3], *bias[3];
};

__global__ void precomp_kernel(PrecompArgs A) {
    int q = blockIdx.x;      // 0..2
    int f = threadIdx.x;     // 0..127
    const float* pwk = A.pwk[q];
    float* Wp = A.Wp[q];
    float bias = A.pwb[q][f];
    for (int c = 0; c < 128; ++c) {
        float rs = rsqrtf(A.var[q][c] + BN_EPS);
        float s = A.g[q][c] * rs;
        float w = pwk[c * 128 + f];
        Wp[c * 128 + f] = s * w;
        bias += (s * (A.dwb[q][c] - A.mu[q][c]) + A.b[q][c]) * w;
    }
    A.bias[q][f] = bias;
}

// ---------------- fused depthwise 3x3 + pointwise 1x1 conv ----------------
struct ConvArgs {
    const float* x;
    const float* dwk[3];
    const float* Wp[3];
    const float* bias[3];
    __bf16* out[3];   // [b*4+h][n][32] bf16
};

__global__ __launch_bounds__(256) void conv_kernel(ConvArgs A) {
    int qkv  = blockIdx.x >> 8;
    int tile = blockIdx.x & 255;
    int b    = tile >> 7;
    int t32  = tile & 127;
    int n0   = t32 * 32;
    int l    = n0 >> 6;     // image row
    int w0   = n0 & 63;     // 0 or 32
    int tid  = threadIdx.x;

    __shared__ float dwl[32][128];

    const float* dwk = A.dwk[qkv];
    // ---- depthwise: each thread = one channel c, 16 pixels ----
    {
        int c  = tid & 127;
        int ph = tid >> 7;          // 0..1
        float kd[9];
#pragma unroll
        for (int t = 0; t < 9; ++t) kd[t] = dwk[t * 128 + c];
        float acc[16];
#pragma unroll
        for (int j = 0; j < 16; ++j) acc[j] = 0.f;
        int wbase = w0 + ph * 16;
        const float* xb = A.x + (size_t)b * NN * CC + c;
#pragma unroll
        for (int dl = 0; dl < 3; ++dl) {
            int ll = l + dl - 1;
            if (ll < 0 || ll >= 64) continue;
#pragma unroll
            for (int wx = 0; wx < 18; ++wx) {
                int ww = wbase + wx - 1;
                if (ww < 0 || ww >= 64) continue;
                float xv = xb[(ll * 64 + ww) * 128];
                if (wx < 16)               acc[wx]     += xv * kd[dl * 3 + 0];
                if (wx >= 1 && wx < 17)    acc[wx - 1] += xv * kd[dl * 3 + 1];
                if (wx >= 2)               acc[wx - 2] += xv * kd[dl * 3 + 2];
            }
        }
#pragma unroll
        for (int j = 0; j < 16; ++j) dwl[ph * 16 + j][c] = acc[j];
    }
    __syncthreads();
    // ---- pointwise GEMM: thread = 4 pixels x 4 features ----
    {
        int fg = tid & 31;    // feature group: f = fg*4..+3
        int pg = tid >> 5;    // pixel group:   p = pg*4..+3
        const float* Wp = A.Wp[qkv];
        float a[4][4];
#pragma unroll
        for (int i = 0; i < 4; ++i)
#pragma unroll
            for (int j = 0; j < 4; ++j) a[i][j] = 0.f;
        for (int c = 0; c < 128; ++c) {
            f32x4 wv = *(const f32x4*)&Wp[c * 128 + fg * 4];
#pragma unroll
            for (int i = 0; i < 4; ++i) {
                float d = dwl[pg * 4 + i][c];
                a[i][0] += d * wv[0];
                a[i][1] += d * wv[1];
                a[i][2] += d * wv[2];
                a[i][3] += d * wv[3];
            }
        }
        f32x4 bs = *(const f32x4*)&A.bias[qkv][fg * 4];
        int f0 = fg * 4;
        int h  = f0 >> 5;
        int dh0 = f0 & 31;
        __bf16* dst = A.out[qkv] + ((size_t)(b * 4 + h) * NN) * 32 + dh0;
#pragma unroll
        for (int i = 0; i < 4; ++i) {
            int n = n0 + pg * 4 + i;
            bf16x4_t v;
            v[0] = (__bf16)(a[i][0] + bs[0]);
            v[1] = (__bf16)(a[i][1] + bs[1]);
            v[2] = (__bf16)(a[i][2] + bs[2]);
            v[3] = (__bf16)(a[i][3] + bs[3]);
            *(bf16x4_t*)(dst + (size_t)n * 32) = v;
        }
    }
}

// ---------------- flash attention, bf16 MFMA ----------------
__global__ __launch_bounds__(512, 1) void attn_kernel(
        const __bf16* __restrict__ qg, const __bf16* __restrict__ kg,
        const __bf16* __restrict__ vg, float* __restrict__ Og) {
    int bid = blockIdx.x;        // 256 blocks
    int bh  = bid >> 5;          // 0..7  (b*4+h)
    int qt  = bid & 31;          // q tile of 128 rows
    int b   = bh >> 2, h = bh & 3;
    int tid = threadIdx.x;
    int wv  = tid >> 6;          // wave 0..7
    int lane = tid & 63;
    int lg  = lane >> 4;         // 0..3
    int lr  = lane & 15;

    __shared__ __bf16 Kl[64][40];      // key-major, padded
    __shared__ __bf16 Vt[32][88];      // dh-major (transposed), padded
    __shared__ __bf16 Pl[8][16][88];   // per-wave P tile, padded

    // Q fragment: row = lr (query), k = lg*8..+7 (dh)
    const __bf16* qrow = qg + ((size_t)bh * NN + qt * 128 + wv * 16 + lr) * 32 + lg * 8;
    bf16x8_t Qf = *(const bf16x8_t*)qrow;
    const __bf16* Kbh = kg + (size_t)bh * NN * 32;
    const __bf16* Vbh = vg + (size_t)bh * NN * 32;

    f32x4 acc0 = {0.f, 0.f, 0.f, 0.f};
    f32x4 acc1 = {0.f, 0.f, 0.f, 0.f};
    f32x4 zero4 = {0.f, 0.f, 0.f, 0.f};
    float mr[4], ls[4];
#pragma unroll
    for (int r = 0; r < 4; ++r) { mr[r] = -1e30f; ls[r] = 0.f; }

    int srow = tid >> 3;         // 0..63
    int sc4  = (tid & 7) * 4;    // 0..28

    for (int t = 0; t < 64; ++t) {
        int k0 = t * 64;
        // ---- stage K (row-major) and V (transposed) ----
        uint2 kkv = *(const uint2*)(Kbh + (size_t)(k0 + srow) * 32 + sc4);
        *(uint2*)&Kl[srow][sc4] = kkv;
        uint2 vvv = *(const uint2*)(Vbh + (size_t)(k0 + srow) * 32 + sc4);
        const __bf16* vp = (const __bf16*)&vvv;
#pragma unroll
        for (int j = 0; j < 4; ++j) Vt[sc4 + j][srow] = vp[j];
        __syncthreads();

        // ---- S = Q K^T over 64 keys (4 x 16-key MFMA) ----
        f32x4 s[4];
#pragma unroll
        for (int kb = 0; kb < 4; ++kb) {
            bf16x8_t Kf = *(const bf16x8_t*)&Kl[lr + kb * 16][lg * 8];
            s[kb] = __builtin_amdgcn_mfma_f32_16x16x32_bf16(Qf, Kf, zero4, 0, 0, 0);
        }
        // ---- online softmax (rows: lg*4+r, cols: lr across 16 lanes) ----
        float pr[4][4];
#pragma unroll
        for (int r = 0; r < 4; ++r) {
            float m = fmaxf(fmaxf(s[0][r], s[1][r]), fmaxf(s[2][r], s[3][r])) * SCALE;
            m = fmaxf(m, __shfl_xor(m, 1));
            m = fmaxf(m, __shfl_xor(m, 2));
            m = fmaxf(m, __shfl_xor(m, 4));
            m = fmaxf(m, __shfl_xor(m, 8));
            float mnew = fmaxf(mr[r], m);
            float alpha = __expf(mr[r] - mnew);
            mr[r] = mnew;
            float rsum = 0.f;
#pragma unroll
            for (int kb = 0; kb < 4; ++kb) {
                float p = __expf(s[kb][r] * SCALE - mnew);
                pr[kb][r] = p;
                rsum += p;
            }
            rsum += __shfl_xor(rsum, 1);
            rsum += __shfl_xor(rsum, 2);
            rsum += __shfl_xor(rsum, 4);
            rsum += __shfl_xor(rsum, 8);
            ls[r] = ls[r] * alpha + rsum;
            acc0[r] *= alpha;
            acc1[r] *= alpha;
        }
        // ---- write P to wave-local LDS (bf16) ----
#pragma unroll
        for (int kb = 0; kb < 4; ++kb)
#pragma unroll
            for (int r = 0; r < 4; ++r)
                Pl[wv][lg * 4 + r][lr + kb * 16] = (__bf16)pr[kb][r];
        __syncthreads();
        // ---- O += P V  (2 key-halves x 2 dh-halves) ----
#pragma unroll
        for (int ks = 0; ks < 2; ++ks) {
            bf16x8_t Pf = *(const bf16x8_t*)&Pl[wv][lr][ks * 32 + lg * 8];
            bf16x8_t V0 = *(const bf16x8_t*)&Vt[lr][ks * 32 + lg * 8];
            bf16x8_t V1 = *(const bf16x8_t*)&Vt[lr + 16][ks * 32 + lg * 8];
            acc0 = __builtin_amdgcn_mfma_f32_16x16x32_bf16(Pf, V0, acc0, 0, 0, 0);
            acc1 = __builtin_amdgcn_mfma_f32_16x16x32_bf16(Pf, V1, acc1, 0, 0, 0);
        }
        __syncthreads();
    }
    // ---- epilogue: normalize and write O[b][n][h*32+dh] (f32) ----
    int nrow = qt * 128 + wv * 16 + lg * 4;
    float* ob = Og + (size_t)b * NN * 128 + (size_t)h * 32;
#pragma unroll
    for (int r = 0; r < 4; ++r) {
        float inv = 1.f / ls[r];
        ob[(size_t)(nrow + r) * 128 + lr]      = acc0[r] * inv;
        ob[(size_t)(nrow + r) * 128 + lr + 16] = acc1[r] * inv;
    }
}

// ---------------- output projection (f32 output — harness reads f32) -------
__global__ __launch_bounds__(256) void outproj_kernel(
        const float* __restrict__ Og, const float* __restrict__ ow,
        const float* __restrict__ obias, float* __restrict__ out) {
    int tile = blockIdx.x;      // 256
    int b = tile >> 7, t32 = tile & 127;
    int n0 = t32 * 32;
    int tid = threadIdx.x;
    __shared__ float Ol[32][128];
#pragma unroll
    for (int r2 = 0; r2 < 16; ++r2) {
        int idx = r2 * 256 + tid;
        int p = idx >> 7, c = idx & 127;
        Ol[p][c] = Og[((size_t)b * NN + n0 + p) * 128 + c];
    }
    __syncthreads();
    int fg = tid & 31, pg = tid >> 5;
    float a[4][4];
#pragma unroll
    for (int i = 0; i < 4; ++i)
#pragma unroll
        for (int j = 0; j < 4; ++j) a[i][j] = 0.f;
    for (int c = 0; c < 128; ++c) {
        f32x4 wv4 = *(const f32x4*)&ow[c * 128 + fg * 4];
#pragma unroll
        for (int i = 0; i < 4; ++i) {
            float d = Ol[pg * 4 + i][c];
            a[i][0] += d * wv4[0];
            a[i][1] += d * wv4[1];
            a[i][2] += d * wv4[2];
            a[i][3] += d * wv4[3];
        }
    }
    f32x4 bs = *(const f32x4*)&obias[fg * 4];
#pragma unroll
    for (int i = 0; i < 4; ++i) {
        int n = n0 + pg * 4 + i;
        f32x4 v;
        v[0] = a[i][0] + bs[0];
        v[1] = a[i][1] + bs[1];
        v[2] = a[i][2] + bs[2];
        v[3] = a[i][3] + bs[3];
        *(f32x4*)(out + ((size_t)b * NN + n) * 128 + fg * 4) = v;
    }
}

extern "C" void kernel_launch(void* const* d_in, const int* in_sizes, int n_in,
                              void* d_out, int out_size, void* d_ws, size_t ws_size,
                              hipStream_t stream) {
    const float* x = (const float*)d_in[0];
    char* ws = (char*)d_ws;

    // workspace layout
    float* Wp[3];
    float* biasp[3];
    __bf16* qkvp[3];
    for (int i = 0; i < 3; ++i) {
        Wp[i]    = (float*)(ws + (size_t)i * 65536);
        biasp[i] = (float*)(ws + 196608 + (size_t)i * 512);
        qkvp[i]  = (__bf16*)(ws + 262144 + (size_t)i * 2097152);
    }
    float* O = (float*)(ws + 262144 + 3 * (size_t)2097152);

    PrecompArgs pa;
    ConvArgs ca;
    ca.x = x;
    for (int i = 0; i < 3; ++i) {
        int base = 1 + 8 * i;
        ca.dwk[i] = (const float*)d_in[base + 0];
        pa.dwb[i] = (const float*)d_in[base + 1];
        pa.g[i]   = (const float*)d_in[base + 2];
        pa.b[i]   = (const float*)d_in[base + 3];
        pa.mu[i]  = (const float*)d_in[base + 4];
        pa.var[i] = (const float*)d_in[base + 5];
        pa.pwk[i] = (const float*)d_in[base + 6];
        pa.pwb[i] = (const float*)d_in[base + 7];
        pa.Wp[i] = Wp[i];
        pa.bias[i] = biasp[i];
        ca.Wp[i] = Wp[i];
        ca.bias[i] = biasp[i];
        ca.out[i] = qkvp[i];
    }

    hipLaunchKernelGGL(precomp_kernel, dim3(3), dim3(128), 0, stream, pa);
    hipLaunchKernelGGL(conv_kernel, dim3(768), dim3(256), 0, stream, ca);
    hipLaunchKernelGGL(attn_kernel, dim3(256), dim3(512), 0, stream,
                       qkvp[0], qkvp[1], qkvp[2], O);
    hipLaunchKernelGGL(outproj_kernel, dim3(256), dim3(256), 0, stream,
                       O, (const float*)d_in[25], (const float*)d_in[26],
                       (float*)d_out);
}

// Round 10
// 293.833 us; speedup vs baseline: 1.1606x; 1.1606x over previous
//
#include <hip/hip_runtime.h>
#include <hip/hip_bf16.h>

#define NN 4096
#define CC 128

typedef __bf16 bf16x8_t __attribute__((ext_vector_type(8)));
typedef __bf16 bf16x4_t __attribute__((ext_vector_type(4)));
typedef float f32x4 __attribute__((ext_vector_type(4)));

static constexpr float SCALE = 0.17677669529663687f;  // 32^-0.5
static constexpr float LOG2E = 1.4426950408889634f;
static constexpr float BN_EPS = 1e-3f;

// ---------------- precompute: fold BN into pointwise weights ----------------
// q-branch additionally folds SCALE*LOG2E so attention scores are in log2 units.
struct PrecompArgs {
    const float *g[3], *b[3], *mu[3], *var[3], *dwb[3], *pwk[3], *pwb[3];
    float *Wp[3], *bias[3];
};

__global__ __launch_bounds__(128) void precomp_kernel(PrecompArgs A) {
    int q = blockIdx.x;      // 0..2
    int f = threadIdx.x;     // 0..127
    __shared__ float sS[128], sB[128];
    {
        int c = f;
        float rs = rsqrtf(A.var[q][c] + BN_EPS);
        float s = A.g[q][c] * rs;
        sS[c] = s;
        sB[c] = s * (A.dwb[q][c] - A.mu[q][c]) + A.b[q][c];
    }
    __syncthreads();
    float qs = (q == 0) ? SCALE * LOG2E : 1.0f;
    const float* pwk = A.pwk[q];
    float* Wp = A.Wp[q];
    float bias = A.pwb[q][f];
    for (int c = 0; c < 128; ++c) {
        float w = pwk[c * 128 + f];          // coalesced across f
        Wp[c * 128 + f] = qs * sS[c] * w;
        bias += sB[c] * w;
    }
    A.bias[q][f] = qs * bias;
}

// ---------------- fused depthwise 3x3 + pointwise 1x1 conv ----------------
struct ConvArgs {
    const float* x;
    const float* dwk[3];
    const float* Wp[3];
    const float* bias[3];
    __bf16* out[3];   // [b*4+h][n][32] bf16
};

__global__ __launch_bounds__(256) void conv_kernel(ConvArgs A) {
    int qkv  = blockIdx.x >> 8;
    int tile = blockIdx.x & 255;
    int b    = tile >> 7;
    int t32  = tile & 127;
    int n0   = t32 * 32;
    int l    = n0 >> 6;     // image row
    int w0   = n0 & 63;     // 0 or 32
    int tid  = threadIdx.x;

    __shared__ float dwl[32][128];

    const float* dwk = A.dwk[qkv];
    // ---- depthwise: each thread = one channel c, 16 pixels ----
    {
        int c  = tid & 127;
        int ph = tid >> 7;          // 0..1
        float kd[9];
#pragma unroll
        for (int t = 0; t < 9; ++t) kd[t] = dwk[t * 128 + c];
        float acc[16];
#pragma unroll
        for (int j = 0; j < 16; ++j) acc[j] = 0.f;
        int wbase = w0 + ph * 16;
        const float* xb = A.x + (size_t)b * NN * CC + c;
#pragma unroll
        for (int dl = 0; dl < 3; ++dl) {
            int ll = l + dl - 1;
            if (ll < 0 || ll >= 64) continue;
#pragma unroll
            for (int wx = 0; wx < 18; ++wx) {
                int ww = wbase + wx - 1;
                if (ww < 0 || ww >= 64) continue;
                float xv = xb[(ll * 64 + ww) * 128];
                if (wx < 16)               acc[wx]     += xv * kd[dl * 3 + 0];
                if (wx >= 1 && wx < 17)    acc[wx - 1] += xv * kd[dl * 3 + 1];
                if (wx >= 2)               acc[wx - 2] += xv * kd[dl * 3 + 2];
            }
        }
#pragma unroll
        for (int j = 0; j < 16; ++j) dwl[ph * 16 + j][c] = acc[j];
    }
    __syncthreads();
    // ---- pointwise GEMM: thread = 4 pixels x 4 features ----
    {
        int fg = tid & 31;    // feature group: f = fg*4..+3
        int pg = tid >> 5;    // pixel group:   p = pg*4..+3
        const float* Wp = A.Wp[qkv];
        float a[4][4];
#pragma unroll
        for (int i = 0; i < 4; ++i)
#pragma unroll
            for (int j = 0; j < 4; ++j) a[i][j] = 0.f;
        for (int c = 0; c < 128; ++c) {
            f32x4 wv = *(const f32x4*)&Wp[c * 128 + fg * 4];
#pragma unroll
            for (int i = 0; i < 4; ++i) {
                float d = dwl[pg * 4 + i][c];
                a[i][0] += d * wv[0];
                a[i][1] += d * wv[1];
                a[i][2] += d * wv[2];
                a[i][3] += d * wv[3];
            }
        }
        f32x4 bs = *(const f32x4*)&A.bias[qkv][fg * 4];
        int f0 = fg * 4;
        int h  = f0 >> 5;
        int dh0 = f0 & 31;
        __bf16* dst = A.out[qkv] + ((size_t)(b * 4 + h) * NN) * 32 + dh0;
#pragma unroll
        for (int i = 0; i < 4; ++i) {
            int n = n0 + pg * 4 + i;
            bf16x4_t v;
            v[0] = (__bf16)(a[i][0] + bs[0]);
            v[1] = (__bf16)(a[i][1] + bs[1]);
            v[2] = (__bf16)(a[i][2] + bs[2]);
            v[3] = (__bf16)(a[i][3] + bs[3]);
            *(bf16x4_t*)(dst + (size_t)n * 32) = v;
        }
    }
}

// ---------------- flash attention: swapped QK^T, register P, 1 barrier/tile
__global__ __launch_bounds__(256, 2) void attn_kernel(
        const __bf16* __restrict__ qg, const __bf16* __restrict__ kg,
        const __bf16* __restrict__ vg, float* __restrict__ Og) {
    int bid = blockIdx.x;        // 512 blocks = qt*8 + bh  (bh -> XCD)
    int bh  = bid & 7;
    int qt  = bid >> 3;          // 0..63, 64 q-rows each
    int b   = bh >> 2, h = bh & 3;
    int tid = threadIdx.x;
    int wv  = tid >> 6;          // wave 0..3, 16 q-rows each
    int lane = tid & 63;
    int lg  = lane >> 4;         // 0..3
    int lr  = lane & 15;

    __shared__ __bf16 Kl[2][64][40];   // [buf][key][dh], padded to 40
    __shared__ __bf16 Vt[2][32][68];   // [buf][dh][key], padded to 68

    const __bf16* Kbh = kg + (size_t)bh * NN * 32;
    const __bf16* Vbh = vg + (size_t)bh * NN * 32;

    // Q fragment (B-operand of swapped QK^T): row = lr, k = lg*8..+7.
    // SCALE*LOG2E already folded into q by precomp.
    int qrow0 = qt * 64 + wv * 16;
    bf16x8_t Qf = *(const bf16x8_t*)(qg + ((size_t)bh * NN + qrow0 + lr) * 32 + lg * 8);

    f32x4 acc0 = {0.f, 0.f, 0.f, 0.f};   // O[qrow=lg*4+r][dh=lr]
    f32x4 acc1 = {0.f, 0.f, 0.f, 0.f};   // O[qrow=lg*4+r][dh=lr+16]
    f32x4 zero4 = {0.f, 0.f, 0.f, 0.f};
    float mr = -1e30f, lsum = 0.f;       // stats for q-row lr (replicated over lg)

    int skey = tid >> 2;          // 0..63
    int sdh8 = (tid & 3) * 8;     // 0,8,16,24

    // ---- prologue: stage tile 0 ----
    {
        uint4 kk = *(const uint4*)(Kbh + (size_t)skey * 32 + sdh8);
        uint4 vv = *(const uint4*)(Vbh + (size_t)skey * 32 + sdh8);
        *(uint4*)&Kl[0][skey][sdh8] = kk;
        const __bf16* vp = (const __bf16*)&vv;
#pragma unroll
        for (int j = 0; j < 8; ++j) Vt[0][sdh8 + j][skey] = vp[j];
    }
    __syncthreads();

    uint4 kk, vv;
    for (int t = 0; t < 64; ++t) {
        int cur = t & 1;
        if (t < 63) {   // issue next-tile loads early; HBM latency hides under MFMA
            int k0n = (t + 1) * 64;
            kk = *(const uint4*)(Kbh + (size_t)(k0n + skey) * 32 + sdh8);
            vv = *(const uint4*)(Vbh + (size_t)(k0n + skey) * 32 + sdh8);
        }
        // ---- S^T = K·Q^T: lane holds S[qrow=lr][key=16kb+4lg+r] ----
        f32x4 s[4];
#pragma unroll
        for (int kb = 0; kb < 4; ++kb) {
            bf16x8_t Kf = *(const bf16x8_t*)&Kl[cur][kb * 16 + lr][lg * 8];
            s[kb] = __builtin_amdgcn_mfma_f32_16x16x32_bf16(Kf, Qf, zero4, 0, 0, 0);
        }
        // ---- online softmax in log2 units, row fully lane-local + 2 shfls ----
        float tm = -1e30f;
#pragma unroll
        for (int kb = 0; kb < 4; ++kb)
#pragma unroll
            for (int r = 0; r < 4; ++r) tm = fmaxf(tm, s[kb][r]);
        tm = fmaxf(tm, __shfl_xor(tm, 16));
        tm = fmaxf(tm, __shfl_xor(tm, 32));
        float mnew = fmaxf(mr, tm);
        float alpha = exp2f(mr - mnew);
        mr = mnew;
        float p[16];
        float rsum = 0.f;
#pragma unroll
        for (int kb = 0; kb < 4; ++kb)
#pragma unroll
            for (int r = 0; r < 4; ++r) {
                float pv = exp2f(s[kb][r] - mnew);
                p[kb * 4 + r] = pv;
                rsum += pv;
            }
        rsum += __shfl_xor(rsum, 16);
        rsum += __shfl_xor(rsum, 32);
        lsum = lsum * alpha + rsum;
        // acc rows are qrow = lg*4+r -> fetch that row's alpha (4 bpermutes)
#pragma unroll
        for (int r = 0; r < 4; ++r) {
            float ao = __shfl(alpha, lg * 4 + r);
            acc0[r] *= ao;
            acc1[r] *= ao;
        }
        // ---- pack P into A-fragments; key map kappa(lg,j)=32m+16(j>>2)+4lg+(j&3)
        bf16x8_t PA0, PA1;
#pragma unroll
        for (int j = 0; j < 8; ++j) {
            PA0[j] = (__bf16)p[j];
            PA1[j] = (__bf16)p[8 + j];
        }
        // ---- PV with the SAME key map on B: no cross-lane P movement needed
#pragma unroll
        for (int m = 0; m < 2; ++m) {
            bf16x8_t Pf = (m == 0) ? PA0 : PA1;
            bf16x4_t a0 = *(const bf16x4_t*)&Vt[cur][lr][32 * m + 4 * lg];
            bf16x4_t a1 = *(const bf16x4_t*)&Vt[cur][lr][32 * m + 16 + 4 * lg];
            bf16x8_t B0;
#pragma unroll
            for (int j = 0; j < 4; ++j) { B0[j] = a0[j]; B0[4 + j] = a1[j]; }
            acc0 = __builtin_amdgcn_mfma_f32_16x16x32_bf16(Pf, B0, acc0, 0, 0, 0);
            bf16x4_t c0 = *(const bf16x4_t*)&Vt[cur][lr + 16][32 * m + 4 * lg];
            bf16x4_t c1 = *(const bf16x4_t*)&Vt[cur][lr + 16][32 * m + 16 + 4 * lg];
            bf16x8_t B1;
#pragma unroll
            for (int j = 0; j < 4; ++j) { B1[j] = c0[j]; B1[4 + j] = c1[j]; }
            acc1 = __builtin_amdgcn_mfma_f32_16x16x32_bf16(Pf, B1, acc1, 0, 0, 0);
        }
        // ---- write next tile (buf[cur^1] was last read in iter t-1; the
        // barrier at the end of iter t-1 ordered those reads before us) ----
        if (t < 63) {
            *(uint4*)&Kl[cur ^ 1][skey][sdh8] = kk;
            const __bf16* vp = (const __bf16*)&vv;
#pragma unroll
            for (int j = 0; j < 8; ++j) Vt[cur ^ 1][sdh8 + j][skey] = vp[j];
        }
        __syncthreads();   // single barrier per tile
    }

    // ---- epilogue: fetch per-row lsum, normalize, write O[b][n][h*32+dh] ----
    float* ob = Og + (size_t)b * NN * 128 + (size_t)h * 32;
    int nrow = qrow0 + lg * 4;
#pragma unroll
    for (int r = 0; r < 4; ++r) {
        float inv = 1.f / __shfl(lsum, lg * 4 + r);
        ob[(size_t)(nrow + r) * 128 + lr]      = acc0[r] * inv;
        ob[(size_t)(nrow + r) * 128 + lr + 16] = acc1[r] * inv;
    }
}

// ---------------- output projection (f32 output) ----------------
__global__ __launch_bounds__(256) void outproj_kernel(
        const float* __restrict__ Og, const float* __restrict__ ow,
        const float* __restrict__ obias, float* __restrict__ out) {
    int tile = blockIdx.x;      // 256
    int b = tile >> 7, t32 = tile & 127;
    int n0 = t32 * 32;
    int tid = threadIdx.x;
    __shared__ float Ol[32][128];
#pragma unroll
    for (int r2 = 0; r2 < 16; ++r2) {
        int idx = r2 * 256 + tid;
        int p = idx >> 7, c = idx & 127;
        Ol[p][c] = Og[((size_t)b * NN + n0 + p) * 128 + c];
    }
    __syncthreads();
    int fg = tid & 31, pg = tid >> 5;
    float a[4][4];
#pragma unroll
    for (int i = 0; i < 4; ++i)
#pragma unroll
        for (int j = 0; j < 4; ++j) a[i][j] = 0.f;
    for (int c = 0; c < 128; ++c) {
        f32x4 wv4 = *(const f32x4*)&ow[c * 128 + fg * 4];
#pragma unroll
        for (int i = 0; i < 4; ++i) {
            float d = Ol[pg * 4 + i][c];
            a[i][0] += d * wv4[0];
            a[i][1] += d * wv4[1];
            a[i][2] += d * wv4[2];
            a[i][3] += d * wv4[3];
        }
    }
    f32x4 bs = *(const f32x4*)&obias[fg * 4];
#pragma unroll
    for (int i = 0; i < 4; ++i) {
        int n = n0 + pg * 4 + i;
        f32x4 v;
        v[0] = a[i][0] + bs[0];
        v[1] = a[i][1] + bs[1];
        v[2] = a[i][2] + bs[2];
        v[3] = a[i][3] + bs[3];
        *(f32x4*)(out + ((size_t)b * NN + n) * 128 + fg * 4) = v;
    }
}

extern "C" void kernel_launch(void* const* d_in, const int* in_sizes, int n_in,
                              void* d_out, int out_size, void* d_ws, size_t ws_size,
                              hipStream_t stream) {
    const float* x = (const float*)d_in[0];
    char* ws = (char*)d_ws;

    // workspace layout
    float* Wp[3];
    float* biasp[3];
    __bf16* qkvp[3];
    for (int i = 0; i < 3; ++i) {
        Wp[i]    = (float*)(ws + (size_t)i * 65536);
        biasp[i] = (float*)(ws + 196608 + (size_t)i * 512);
        qkvp[i]  = (__bf16*)(ws + 262144 + (size_t)i * 2097152);
    }
    float* O = (float*)(ws + 262144 + 3 * (size_t)2097152);

    PrecompArgs pa;
    ConvArgs ca;
    ca.x = x;
    for (int i = 0; i < 3; ++i) {
        int base = 1 + 8 * i;
        ca.dwk[i] = (const float*)d_in[base + 0];
        pa.dwb[i] = (const float*)d_in[base + 1];
        pa.g[i]   = (const float*)d_in[base + 2];
        pa.b[i]   = (const float*)d_in[base + 3];
        pa.mu[i]  = (const float*)d_in[base + 4];
        pa.var[i] = (const float*)d_in[base + 5];
        pa.pwk[i] = (const float*)d_in[base + 6];
        pa.pwb[i] = (const float*)d_in[base + 7];
        pa.Wp[i] = Wp[i];
        pa.bias[i] = biasp[i];
        ca.Wp[i] = Wp[i];
        ca.bias[i] = biasp[i];
        ca.out[i] = qkvp[i];
    }

    hipLaunchKernelGGL(precomp_kernel, dim3(3), dim3(128), 0, stream, pa);
    hipLaunchKernelGGL(conv_kernel, dim3(768), dim3(256), 0, stream, ca);
    hipLaunchKernelGGL(attn_kernel, dim3(512), dim3(256), 0, stream,
                       qkvp[0], qkvp[1], qkvp[2], O);
    hipLaunchKernelGGL(outproj_kernel, dim3(256), dim3(256), 0, stream,
                       O, (const float*)d_in[25], (const float*)d_in[26],
                       (float*)d_out);
}

// Round 12
// 277.263 us; speedup vs baseline: 1.2299x; 1.0598x over previous
//
#include <hip/hip_runtime.h>
#include <hip/hip_bf16.h>

#define NN 4096
#define CC 128

typedef __bf16 bf16x8_t __attribute__((ext_vector_type(8)));
typedef __bf16 bf16x4_t __attribute__((ext_vector_type(4)));
typedef float f32x4 __attribute__((ext_vector_type(4)));

static constexpr float SCALE = 0.17677669529663687f;  // 32^-0.5
static constexpr float LOG2E = 1.4426950408889634f;
static constexpr float BN_EPS = 1e-3f;

// ---------------- precompute: fold BN into pointwise weights ----------------
// q-branch additionally folds SCALE*LOG2E so attention scores are in log2 units.
struct PrecompArgs {
    const float *g[3], *b[3], *mu[3], *var[3], *dwb[3], *pwk[3], *pwb[3];
    float *Wp[3], *bias[3];
};

__global__ __launch_bounds__(128) void precomp_kernel(PrecompArgs A) {
    int q = blockIdx.x;      // 0..2
    int f = threadIdx.x;     // 0..127
    __shared__ float sS[128], sB[128];
    {
        int c = f;
        float rs = rsqrtf(A.var[q][c] + BN_EPS);
        float s = A.g[q][c] * rs;
        sS[c] = s;
        sB[c] = s * (A.dwb[q][c] - A.mu[q][c]) + A.b[q][c];
    }
    __syncthreads();
    float qs = (q == 0) ? SCALE * LOG2E : 1.0f;
    const float* pwk = A.pwk[q];
    float* Wp = A.Wp[q];
    float bias = A.pwb[q][f];
    for (int c = 0; c < 128; ++c) {
        float w = pwk[c * 128 + f];          // coalesced across f
        Wp[c * 128 + f] = qs * sS[c] * w;
        bias += sB[c] * w;
    }
    A.bias[q][f] = qs * bias;
}

// ---------------- fused depthwise 3x3 + pointwise 1x1 conv ----------------
struct ConvArgs {
    const float* x;
    const float* dwk[3];
    const float* Wp[3];
    const float* bias[3];
    __bf16* out[3];   // [b*4+h][n][32] bf16
};

__global__ __launch_bounds__(256) void conv_kernel(ConvArgs A) {
    int qkv  = blockIdx.x >> 8;
    int tile = blockIdx.x & 255;
    int b    = tile >> 7;
    int t32  = tile & 127;
    int n0   = t32 * 32;
    int l    = n0 >> 6;     // image row
    int w0   = n0 & 63;     // 0 or 32
    int tid  = threadIdx.x;

    __shared__ float dwl[32][128];

    const float* dwk = A.dwk[qkv];
    // ---- depthwise: each thread = one channel c, 16 pixels ----
    {
        int c  = tid & 127;
        int ph = tid >> 7;          // 0..1
        float kd[9];
#pragma unroll
        for (int t = 0; t < 9; ++t) kd[t] = dwk[t * 128 + c];
        float acc[16];
#pragma unroll
        for (int j = 0; j < 16; ++j) acc[j] = 0.f;
        int wbase = w0 + ph * 16;
        const float* xb = A.x + (size_t)b * NN * CC + c;
#pragma unroll
        for (int dl = 0; dl < 3; ++dl) {
            int ll = l + dl - 1;
            if (ll < 0 || ll >= 64) continue;
#pragma unroll
            for (int wx = 0; wx < 18; ++wx) {
                int ww = wbase + wx - 1;
                if (ww < 0 || ww >= 64) continue;
                float xv = xb[(ll * 64 + ww) * 128];
                if (wx < 16)               acc[wx]     += xv * kd[dl * 3 + 0];
                if (wx >= 1 && wx < 17)    acc[wx - 1] += xv * kd[dl * 3 + 1];
                if (wx >= 2)               acc[wx - 2] += xv * kd[dl * 3 + 2];
            }
        }
#pragma unroll
        for (int j = 0; j < 16; ++j) dwl[ph * 16 + j][c] = acc[j];
    }
    __syncthreads();
    // ---- pointwise GEMM: thread = 4 pixels x 4 features ----
    {
        int fg = tid & 31;    // feature group: f = fg*4..+3
        int pg = tid >> 5;    // pixel group:   p = pg*4..+3
        const float* Wp = A.Wp[qkv];
        float a[4][4];
#pragma unroll
        for (int i = 0; i < 4; ++i)
#pragma unroll
            for (int j = 0; j < 4; ++j) a[i][j] = 0.f;
        for (int c = 0; c < 128; ++c) {
            f32x4 wv = *(const f32x4*)&Wp[c * 128 + fg * 4];
#pragma unroll
            for (int i = 0; i < 4; ++i) {
                float d = dwl[pg * 4 + i][c];
                a[i][0] += d * wv[0];
                a[i][1] += d * wv[1];
                a[i][2] += d * wv[2];
                a[i][3] += d * wv[3];
            }
        }
        f32x4 bs = *(const f32x4*)&A.bias[qkv][fg * 4];
        int f0 = fg * 4;
        int h  = f0 >> 5;
        int dh0 = f0 & 31;
        __bf16* dst = A.out[qkv] + ((size_t)(b * 4 + h) * NN) * 32 + dh0;
#pragma unroll
        for (int i = 0; i < 4; ++i) {
            int n = n0 + pg * 4 + i;
            bf16x4_t v;
            v[0] = (__bf16)(a[i][0] + bs[0]);
            v[1] = (__bf16)(a[i][1] + bs[1]);
            v[2] = (__bf16)(a[i][2] + bs[2]);
            v[3] = (__bf16)(a[i][3] + bs[3]);
            *(bf16x4_t*)(dst + (size_t)n * 32) = v;
        }
    }
}

// ---------------- flash attention: split-K wave pairs, K in registers ------
// Block: 32 q-rows x full keys. Waves (qsub = wv&1, khalf = wv>>1):
// wave handles q-rows [qt*32+qsub*16, +16) over keys [khalf*2048, +2048).
// Swapped QK^T (mfma(K,Q)) keeps the key-row lane-local; P never leaves regs.
__global__ __launch_bounds__(256, 4) void attn_kernel(
        const __bf16* __restrict__ qg, const __bf16* __restrict__ kg,
        const __bf16* __restrict__ vg, float* __restrict__ Og) {
    int bid = blockIdx.x;        // 1024 blocks = qt(128) * 8 + bh (bh -> XCD)
    int bh  = bid & 7;
    int qt  = bid >> 3;          // 0..127, 32 q-rows each
    int b   = bh >> 2, h = bh & 3;
    int tid = threadIdx.x;
    int wv  = tid >> 6;          // wave 0..3
    int lane = tid & 63;
    int lg  = lane >> 4;         // 0..3
    int lr  = lane & 15;
    int qsub  = wv & 1;
    int khalf = wv >> 1;

    __shared__ __bf16 Vt[2][2][32][68];   // [buf][khalf][dh][key] (2-way-free stores)

    const __bf16* Kbh = kg + (size_t)bh * NN * 32;
    const __bf16* Vbh = vg + (size_t)bh * NN * 32;

    int qrow0 = qt * 32 + qsub * 16;
    bf16x8_t Qf = *(const bf16x8_t*)(qg + ((size_t)bh * NN + qrow0 + lr) * 32 + lg * 8);
    const __bf16* Kw = Kbh + (size_t)khalf * 2048 * 32;

    f32x4 acc0 = {0.f, 0.f, 0.f, 0.f};
    f32x4 acc1 = {0.f, 0.f, 0.f, 0.f};
    f32x4 zero4 = {0.f, 0.f, 0.f, 0.f};
    float mr = -1e30f, lsum = 0.f;

    // V staging: 256 threads cover 2 halves x 64 keys x 32 dh per tile
    int shalf = tid >> 7;           // 0/1
    int st    = tid & 127;
    int skey  = st >> 1;            // 0..63
    int sdh   = (st & 1) * 16;      // 0 or 16
    const __bf16* Vw = Vbh + (size_t)shalf * 2048 * 32;

    // ---- prologue: stage V tile 0; prefetch K frags tile 0 ----
    {
        bf16x8_t v0 = *(const bf16x8_t*)(Vw + (size_t)skey * 32 + sdh);
        bf16x8_t v1 = *(const bf16x8_t*)(Vw + (size_t)skey * 32 + sdh + 8);
#pragma unroll
        for (int j = 0; j < 8; ++j) {
            Vt[0][shalf][sdh + j][skey]     = v0[j];
            Vt[0][shalf][sdh + 8 + j][skey] = v1[j];
        }
    }
    bf16x8_t kf[4], kfn[4];
#pragma unroll
    for (int kb = 0; kb < 4; ++kb)
        kf[kb] = *(const bf16x8_t*)(Kw + (size_t)(kb * 16 + lr) * 32 + lg * 8);
    __syncthreads();

    bf16x8_t vv0, vv1;
    for (int t = 0; t < 32; ++t) {
        int cur = t & 1;
        if (t < 31) {   // issue next-tile global loads; latency hides under compute
            int k0n = (t + 1) * 64;
            vv0 = *(const bf16x8_t*)(Vw + (size_t)(k0n + skey) * 32 + sdh);
            vv1 = *(const bf16x8_t*)(Vw + (size_t)(k0n + skey) * 32 + sdh + 8);
#pragma unroll
            for (int kb = 0; kb < 4; ++kb)
                kfn[kb] = *(const bf16x8_t*)(Kw + (size_t)(k0n + kb * 16 + lr) * 32 + lg * 8);
        }
        // ---- S^T = K·Q^T: lane holds S[qrow=lr][key=16kb+4lg+r] ----
        f32x4 s[4];
#pragma unroll
        for (int kb = 0; kb < 4; ++kb)
            s[kb] = __builtin_amdgcn_mfma_f32_16x16x32_bf16(kf[kb], Qf, zero4, 0, 0, 0);
        // ---- online softmax (log2 units), defer-max ----
        float tm = -1e30f;
#pragma unroll
        for (int kb = 0; kb < 4; ++kb)
#pragma unroll
            for (int r = 0; r < 4; ++r) tm = fmaxf(tm, s[kb][r]);
        tm = fmaxf(tm, __shfl_xor(tm, 16));
        tm = fmaxf(tm, __shfl_xor(tm, 32));
        bool need = __any(tm > mr + 8.0f);
        float mnew = need ? fmaxf(mr, tm) : mr;
        float p[16];
        float rsum = 0.f;
#pragma unroll
        for (int kb = 0; kb < 4; ++kb)
#pragma unroll
            for (int r = 0; r < 4; ++r) {
                float pv = exp2f(s[kb][r] - mnew);
                p[kb * 4 + r] = pv;
                rsum += pv;
            }
        rsum += __shfl_xor(rsum, 16);
        rsum += __shfl_xor(rsum, 32);
        if (need) {
            float alpha = exp2f(mr - mnew);
            lsum = lsum * alpha + rsum;
#pragma unroll
            for (int r = 0; r < 4; ++r) {
                float ao = __shfl(alpha, lg * 4 + r);
                acc0[r] *= ao;
                acc1[r] *= ao;
            }
            mr = mnew;
        } else {
            lsum += rsum;
        }
        // ---- pack P into A-fragments; key map kappa(lg,j)=32m+16(j>>2)+4lg+(j&3)
        bf16x8_t PA0, PA1;
#pragma unroll
        for (int j = 0; j < 8; ++j) {
            PA0[j] = (__bf16)p[j];
            PA1[j] = (__bf16)p[8 + j];
        }
        // ---- PV with the same key map on B ----
#pragma unroll
        for (int m = 0; m < 2; ++m) {
            bf16x8_t Pf = (m == 0) ? PA0 : PA1;
            bf16x4_t a0 = *(const bf16x4_t*)&Vt[cur][khalf][lr][32 * m + 4 * lg];
            bf16x4_t a1 = *(const bf16x4_t*)&Vt[cur][khalf][lr][32 * m + 16 + 4 * lg];
            bf16x8_t B0;
#pragma unroll
            for (int j = 0; j < 4; ++j) { B0[j] = a0[j]; B0[4 + j] = a1[j]; }
            acc0 = __builtin_amdgcn_mfma_f32_16x16x32_bf16(Pf, B0, acc0, 0, 0, 0);
            bf16x4_t c0 = *(const bf16x4_t*)&Vt[cur][khalf][lr + 16][32 * m + 4 * lg];
            bf16x4_t c1 = *(const bf16x4_t*)&Vt[cur][khalf][lr + 16][32 * m + 16 + 4 * lg];
            bf16x8_t B1;
#pragma unroll
            for (int j = 0; j < 4; ++j) { B1[j] = c0[j]; B1[4 + j] = c1[j]; }
            acc1 = __builtin_amdgcn_mfma_f32_16x16x32_bf16(Pf, B1, acc1, 0, 0, 0);
        }
        // ---- write next V tile; K frags rotate in registers ----
        if (t < 31) {
#pragma unroll
            for (int j = 0; j < 8; ++j) {
                Vt[cur ^ 1][shalf][sdh + j][skey]     = vv0[j];
                Vt[cur ^ 1][shalf][sdh + 8 + j][skey] = vv1[j];
            }
#pragma unroll
            for (int kb = 0; kb < 4; ++kb) kf[kb] = kfn[kb];
        }
        __syncthreads();   // single barrier per tile
    }

    // ---- split-K merge: waves 2,3 publish state; waves 0,1 combine + write --
    float* mrg = (float*)&Vt[0][0][0][0];
    if (wv >= 2) {
        float* d = mrg + ((wv - 2) * 64 + lane) * 12;
#pragma unroll
        for (int r = 0; r < 4; ++r) { d[r] = acc0[r]; d[4 + r] = acc1[r]; }
        d[8] = mr; d[9] = lsum;
    }
    __syncthreads();
    if (wv < 2) {
        const float* d = mrg + (wv * 64 + lane) * 12;
        f32x4 pacc0, pacc1;
#pragma unroll
        for (int r = 0; r < 4; ++r) { pacc0[r] = d[r]; pacc1[r] = d[4 + r]; }
        float pm = d[8], pl = d[9];
        float m  = fmaxf(mr, pm);
        float a  = exp2f(mr - m);
        float pa = exp2f(pm - m);
        float l  = lsum * a + pl * pa;
        float* ob = Og + (size_t)b * NN * 128 + (size_t)h * 32;
        int nrow = qrow0 + lg * 4;
#pragma unroll
        for (int r = 0; r < 4; ++r) {
            float ar  = __shfl(a,  lg * 4 + r);
            float par = __shfl(pa, lg * 4 + r);
            float inv = 1.f / __shfl(l, lg * 4 + r);
            float o0 = acc0[r] * ar + pacc0[r] * par;
            float o1 = acc1[r] * ar + pacc1[r] * par;
            ob[(size_t)(nrow + r) * 128 + lr]      = o0 * inv;
            ob[(size_t)(nrow + r) * 128 + lr + 16] = o1 * inv;
        }
    }
}

// ---------------- output projection (f32 output) ----------------
__global__ __launch_bounds__(256) void outproj_kernel(
        const float* __restrict__ Og, const float* __restrict__ ow,
        const float* __restrict__ obias, float* __restrict__ out) {
    int tile = blockIdx.x;      // 256
    int b = tile >> 7, t32 = tile & 127;
    int n0 = t32 * 32;
    int tid = threadIdx.x;
    __shared__ float Ol[32][128];
#pragma unroll
    for (int r2 = 0; r2 < 16; ++r2) {
        int idx = r2 * 256 + tid;
        int p = idx >> 7, c = idx & 127;
        Ol[p][c] = Og[((size_t)b * NN + n0 + p) * 128 + c];
    }
    __syncthreads();
    int fg = tid & 31, pg = tid >> 5;
    float a[4][4];
#pragma unroll
    for (int i = 0; i < 4; ++i)
#pragma unroll
        for (int j = 0; j < 4; ++j) a[i][j] = 0.f;
    for (int c = 0; c < 128; ++c) {
        f32x4 wv4 = *(const f32x4*)&ow[c * 128 + fg * 4];
#pragma unroll
        for (int i = 0; i < 4; ++i) {
            float d = Ol[pg * 4 + i][c];
            a[i][0] += d * wv4[0];
            a[i][1] += d * wv4[1];
            a[i][2] += d * wv4[2];
            a[i][3] += d * wv4[3];
        }
    }
    f32x4 bs = *(const f32x4*)&obias[fg * 4];
#pragma unroll
    for (int i = 0; i < 4; ++i) {
        int n = n0 + pg * 4 + i;
        f32x4 v;
        v[0] = a[i][0] + bs[0];
        v[1] = a[i][1] + bs[1];
        v[2] = a[i][2] + bs[2];
        v[3] = a[i][3] + bs[3];
        *(f32x4*)(out + ((size_t)b * NN + n) * 128 + fg * 4) = v;
    }
}

extern "C" void kernel_launch(void* const* d_in, const int* in_sizes, int n_in,
                              void* d_out, int out_size, void* d_ws, size_t ws_size,
                              hipStream_t stream) {
    const float* x = (const float*)d_in[0];
    char* ws = (char*)d_ws;

    // workspace layout
    float* Wp[3];
    float* biasp[3];
    __bf16* qkvp[3];
    for (int i = 0; i < 3; ++i) {
        Wp[i]    = (float*)(ws + (size_t)i * 65536);
        biasp[i] = (float*)(ws + 196608 + (size_t)i * 512);
        qkvp[i]  = (__bf16*)(ws + 262144 + (size_t)i * 2097152);
    }
    float* O = (float*)(ws + 262144 + 3 * (size_t)2097152);

    PrecompArgs pa;
    ConvArgs ca;
    ca.x = x;
    for (int i = 0; i < 3; ++i) {
        int base = 1 + 8 * i;
        ca.dwk[i] = (const float*)d_in[base + 0];
        pa.dwb[i] = (const float*)d_in[base + 1];
        pa.g[i]   = (const float*)d_in[base + 2];
        pa.b[i]   = (const float*)d_in[base + 3];
        pa.mu[i]  = (const float*)d_in[base + 4];
        pa.var[i] = (const float*)d_in[base + 5];
        pa.pwk[i] = (const float*)d_in[base + 6];
        pa.pwb[i] = (const float*)d_in[base + 7];
        pa.Wp[i] = Wp[i];
        pa.bias[i] = biasp[i];
        ca.Wp[i] = Wp[i];
        ca.bias[i] = biasp[i];
        ca.out[i] = qkvp[i];
    }

    hipLaunchKernelGGL(precomp_kernel, dim3(3), dim3(128), 0, stream, pa);
    hipLaunchKernelGGL(conv_kernel, dim3(768), dim3(256), 0, stream, ca);
    hipLaunchKernelGGL(attn_kernel, dim3(1024), dim3(256), 0, stream,
                       qkvp[0], qkvp[1], qkvp[2], O);
    hipLaunchKernelGGL(outproj_kernel, dim3(256), dim3(256), 0, stream,
                       O, (const float*)d_in[25], (const float*)d_in[26],
                       (float*)d_out);
}